// Round 5
// baseline (251.643 us; speedup 1.0000x reference)
//
#include <hip/hip_runtime.h>
#include <hip/hip_bf16.h>

#define TDIM 2048
#define FDIM 128
#define NWAVES 8

typedef __attribute__((ext_vector_type(8))) short short8;
typedef __attribute__((ext_vector_type(4))) float f32x4;
typedef __attribute__((ext_vector_type(4))) unsigned uint4v;

__device__ __forceinline__ unsigned short f2bf(float v) {
    __bf16 h = (__bf16)v;
    return __builtin_bit_cast(unsigned short, h);
}

// ---------------- weight prep -> bf16 in d_ws ----------------
// elements (bf16):
//  wt1 @ 0     : [2 cot][4 kb][16 co][8 e]   k=kb*8+e, uv=k>>1, ch=k&1; 0 for k>=18   1024
//  wt2 @ 1024  : [4 g][9 uv][32 co][8 ci]                                             9216
//  wt3 @ 10240 : [4 g][9 uv][32 co][8 ci]                                             9216
//  wt4 @ 19456 : [4 g][9 uv][16 co][8 ci]  (co>0 zero)                                4608
__global__ void prep_weights_kernel(const float* __restrict__ W1, const float* __restrict__ W2,
                                    const float* __restrict__ W3, const float* __restrict__ W4,
                                    unsigned short* __restrict__ wt)
{
    for (int e = blockIdx.x * 256 + threadIdx.x; e < 24064; e += gridDim.x * 256) {
        float v = 0.0f;
        if (e < 1024) {
            int cot = e >> 9, kb = (e >> 7) & 3, co16 = (e >> 3) & 15, ee = e & 7;
            int k = kb * 8 + ee, uv = k >> 1, ch = k & 1, co = cot * 16 + co16;
            if (uv < 9) v = W1[co * 18 + ch * 9 + uv];
        } else if (e < 10240) {
            int q = e - 1024;
            int g = q / 2304, r = q % 2304;
            int uv = r >> 8, co = (r >> 3) & 31, ci = g * 8 + (r & 7);
            v = W2[co * 288 + ci * 9 + uv];
        } else if (e < 19456) {
            int q = e - 10240;
            int g = q / 2304, r = q % 2304;
            int uv = r >> 8, co = (r >> 3) & 31, ci = g * 8 + (r & 7);
            v = W3[co * 288 + ci * 9 + uv];
        } else {
            int q = e - 19456;
            int g = q / 1152, r = q % 1152;
            int uv = r >> 7, co = (r >> 3) & 15, ci = g * 8 + (r & 7);
            if (co == 0) v = W4[ci * 9 + uv];
        }
        wt[e] = f2bf(v);
    }
}

__device__ __forceinline__ uint2 pack4(f32x4 c, bool valid) {
    unsigned short h[4];
#pragma unroll
    for (int k = 0; k < 4; ++k) {
        float v = fmaxf(c[k], 0.0f);
        h[k] = valid ? f2bf(v) : (unsigned short)0;
    }
    uint2 r;
    r.x = (unsigned)h[0] | ((unsigned)h[1] << 16);
    r.y = (unsigned)h[2] | ((unsigned)h[3] << 16);
    return r;
}

// conv2/conv3: in planes [4][WI*WI][16B] -> out planes [4][WO*WO][16B]
// weights in LDS planes [4 g][9 uv][32 co][16B]
template<int WI, int WO, int PSI, int PSO, bool EDGE>
__device__ __forceinline__ void conv_mid(const char* __restrict__ inb, char* __restrict__ outb,
                                         const char* __restrict__ wlds, const float* __restrict__ bias,
                                         int wave, int lane, int t_base, int f_base)
{
    const int lm = lane & 15, g = lane >> 4;
    const char* wp = wlds + g * 4608;
    short8 wa0[9], wa1[9];
#pragma unroll
    for (int uv = 0; uv < 9; ++uv) {
        wa0[uv] = *(const short8*)(wp + (uv * 32 + lm) * 16);
        wa1[uv] = *(const short8*)(wp + (uv * 32 + 16 + lm) * 16);
    }
    f32x4 bias0 = *(const f32x4*)(bias + g * 4);
    f32x4 bias1 = *(const f32x4*)(bias + 16 + g * 4);
    const f32x4 zero = {0.0f, 0.0f, 0.0f, 0.0f};

    const char* inp = inb + g * PSI;
    constexpr int NPX = WO * WO;
    constexpr int NG = (NPX + 15) / 16;
    for (int grp = wave; grp < NG; grp += NWAVES) {
        int m = grp * 16 + lm;
        bool mv = m < NPX;
        int mc = mv ? m : NPX - 1;
        int i = mc / WO, j = mc - i * WO;
        const char* base = inp + (i * WI + j) * 16;
        // 4 independent accumulator chains (uv 0-4 / 5-8) x (co-tile 0/1)
        f32x4 c0a = bias0, c0b = zero, c1a = bias1, c1b = zero;
#pragma unroll
        for (int uv = 0; uv < 9; ++uv) {
            int u = uv / 3, v = uv - u * 3;
            short8 bf = *(const short8*)(base + (u * WI + v) * 16);
            if (uv < 5) {
                c0a = __builtin_amdgcn_mfma_f32_16x16x32_bf16(wa0[uv], bf, c0a, 0, 0, 0);
                c1a = __builtin_amdgcn_mfma_f32_16x16x32_bf16(wa1[uv], bf, c1a, 0, 0, 0);
            } else {
                c0b = __builtin_amdgcn_mfma_f32_16x16x32_bf16(wa0[uv], bf, c0b, 0, 0, 0);
                c1b = __builtin_amdgcn_mfma_f32_16x16x32_bf16(wa1[uv], bf, c1b, 0, 0, 0);
            }
        }
        if (mv) {
            bool valid = true;
            if (EDGE) {
                int t = t_base + i, f = f_base + j;
                valid = (t >= 0) && (t < TDIM) && (f >= 0) && (f < FDIM);
            }
            char* wb = outb + (g >> 1) * PSO + m * 16 + (g & 1) * 8;
            *(uint2*)wb             = pack4(c0a + c0b, valid);
            *(uint2*)(wb + 2 * PSO) = pack4(c1a + c1b, valid);
        }
    }
}

// LDS layout (bytes):
//  X4 [0, 2304)        : [576 px][4B]  (bf16 pr, bf16 onset)   (dead after conv1)
//  Y2 [2304, 27904)    : planes [4][400][16]
//  Y1 [27904, 58880)   : planes [4][484][16]  (dead after conv2)
//  Y3 [27904, 48640)   : planes [4][324][16]  (over dead Y1)
//  WB [58880, 77312)   : [4 g][9 uv][32 co][16B]  (W2; then W3; then W4 [4][9][16][16B])
template<bool EDGE>
__global__ __launch_bounds__(512, 4)
void fused_mfma_kernel(const float* __restrict__ pr, const float* __restrict__ onset,
                       const int* __restrict__ tf,
                       const float* __restrict__ b1, const float* __restrict__ b2,
                       const float* __restrict__ b3, const float* __restrict__ b4,
                       const unsigned short* __restrict__ wt, float* __restrict__ out)
{
    __shared__ __attribute__((aligned(16))) char lds[77312];

    const int tid = threadIdx.x;
    const int lane = tid & 63, wave = tid >> 6;
    int f0, t0;
    if (EDGE) {
        int id = blockIdx.x;
        int bx, by;
        if (id < 128)      { bx = 0; by = id; }
        else if (id < 256) { bx = 7; by = id - 128; }
        else {
            int q = id - 256;
            if (q < 6) { bx = 1 + q; by = 0; }
            else       { bx = 1 + (q - 6); by = 127; }
        }
        f0 = bx * 16; t0 = by * 16;
    } else {
        f0 = (blockIdx.x + 1) * 16;
        t0 = (blockIdx.y + 1) * 16;
    }
    const int b = blockIdx.z;

    unsigned* X4 = (unsigned*)lds;
    char* Y2 = lds + 2304;
    char* Y1 = lds + 27904;
    char* Y3 = lds + 27904;
    char* WB = lds + 58880;
    const char* wtb = (const char*)wt;

    // ---- stage W2 -> WB (1152 x 16B) ----
    for (int ch = tid; ch < 1152; ch += 512)
        *(short8*)(WB + ch * 16) = *(const short8*)(wtb + 2048 + ch * 16);

    // ---- stage X4 [24][24] with per-pixel tatum search ----
    for (int p = tid; p < 576; p += 512) {
        int i = p / 24, j = p - (p / 24) * 24;
        int t = t0 - 4 + i, f = f0 - 4 + j;
        unsigned xv = 0u;
        bool valid = true;
        if (EDGE) valid = (t >= 0) && (t < TDIM) && (f >= 0) && (f < FDIM);
        if (valid) {
            // branchless upper_bound over tf[b*257+1 .. b*257+256] (256 entries):
            // pos = #entries <= t  ==  searchsorted(tf[1:], t, 'right')
            const int* a = tf + b * 257 + 1;
            int pos = 0;
#pragma unroll
            for (int step = 128; step >= 1; step >>= 1) {
                // max read index: pos+step-1 <= 254 < 256 (pos <= 256-2*step inductively)
                pos += (a[pos + step - 1] <= t) ? step : 0;
            }
            int idx = pos < 255 ? pos : 255;
            float v0 = pr[(b * 256 + idx) * 128 + f];
            float v1 = onset[b * 256 + idx];
            xv = (unsigned)f2bf(v0) | ((unsigned)f2bf(v1) << 16);
        }
        X4[p] = xv;
    }
    __syncthreads();

    const int lm = lane & 15, g = lane >> 4;

    // ---- conv1: K=32 packed (k=uv*2+ch), A from global wt1, X4 -> Y1 ----
    {
        const short8 waA = *(const short8*)(wtb + (g * 16 + lm) * 16);
        const short8 waB = *(const short8*)(wtb + (64 + g * 16 + lm) * 16);
        int off4[4];
#pragma unroll
        for (int q = 0; q < 4; ++q) {
            int uv = g * 4 + q;
            int uvc = uv <= 8 ? uv : 8;     // weights zero beyond uv=8; clamp address only
            int u = uvc / 3, v = uvc - u * 3;
            off4[q] = u * 24 + v;
        }
        f32x4 bias0 = *(const f32x4*)(b1 + g * 4);
        f32x4 bias1 = *(const f32x4*)(b1 + 16 + g * 4);

        constexpr int NPX = 22 * 22;
        constexpr int NG = (NPX + 15) / 16;   // 31
        for (int grp = wave; grp < NG; grp += NWAVES) {
            int m = grp * 16 + lm;
            bool mv = m < NPX;
            int mc = mv ? m : NPX - 1;
            int i = mc / 22, j = mc - i * 22;
            int base4 = i * 24 + j;
            uint4v bu;
#pragma unroll
            for (int q = 0; q < 4; ++q) bu[q] = X4[base4 + off4[q]];
            short8 bf = __builtin_bit_cast(short8, bu);
            f32x4 c0 = __builtin_amdgcn_mfma_f32_16x16x32_bf16(waA, bf, bias0, 0, 0, 0);
            f32x4 c1 = __builtin_amdgcn_mfma_f32_16x16x32_bf16(waB, bf, bias1, 0, 0, 0);
            if (mv) {
                bool valid = true;
                if (EDGE) {
                    int t = t0 - 3 + i, f = f0 - 3 + j;
                    valid = (t >= 0) && (t < TDIM) && (f >= 0) && (f < FDIM);
                }
                char* wb = Y1 + (g >> 1) * 7744 + m * 16 + (g & 1) * 8;
                *(uint2*)wb           = pack4(c0, valid);
                *(uint2*)(wb + 15488) = pack4(c1, valid);
            }
        }
    }

    // prefetch W3 into registers (hidden under conv2)
    short8 w3p0 = *(const short8*)(wtb + 20480 + tid * 16);
    short8 w3p1 = *(const short8*)(wtb + 20480 + (tid + 512) * 16);
    short8 w3p2;
    if (tid < 128) w3p2 = *(const short8*)(wtb + 20480 + (tid + 1024) * 16);
    __syncthreads();

    conv_mid<22, 20, 7744, 6400, EDGE>(Y1, Y2, WB, b2, wave, lane, t0 - 2, f0 - 2);
    __syncthreads();

    // write prefetched W3 into WB
    *(short8*)(WB + tid * 16) = w3p0;
    *(short8*)(WB + (tid + 512) * 16) = w3p1;
    if (tid < 128) *(short8*)(WB + (tid + 1024) * 16) = w3p2;
    __syncthreads();

    // prefetch W4 into registers (hidden under conv3) -- written after conv3
    short8 w4p0 = *(const short8*)(wtb + 38912 + tid * 16);
    short8 w4p1;
    if (tid < 64) w4p1 = *(const short8*)(wtb + 38912 + (tid + 512) * 16);

    conv_mid<20, 18, 6400, 5184, EDGE>(Y2, Y3, WB, b3, wave, lane, t0 - 1, f0 - 1);
    __syncthreads();

    *(short8*)(WB + tid * 16) = w4p0;
    if (tid < 64) *(short8*)(WB + (tid + 512) * 16) = w4p1;
    __syncthreads();

    // ---- conv4: Y3 planes [4][324][16] -> out 16x16 fp32; W4 [4 g][9 uv][16 co][16B] ----
    {
        const char* wp = WB + g * 2304;
        short8 wa[9];
#pragma unroll
        for (int uv = 0; uv < 9; ++uv)
            wa[uv] = *(const short8*)(wp + (uv * 16 + lm) * 16);
        float bv = b4[0];
        const char* yp = Y3 + g * 5184;
        const f32x4 zero = {0.0f, 0.0f, 0.0f, 0.0f};
        for (int grp = wave; grp < 16; grp += NWAVES) {
            const char* base = yp + (grp * 18 + lm) * 16;
            f32x4 ca = zero, cb = zero;
#pragma unroll
            for (int uv = 0; uv < 9; ++uv) {
                int u = uv / 3, v = uv - u * 3;
                short8 bf = *(const short8*)(base + (u * 18 + v) * 16);
                if (uv < 5) ca = __builtin_amdgcn_mfma_f32_16x16x32_bf16(wa[uv], bf, ca, 0, 0, 0);
                else        cb = __builtin_amdgcn_mfma_f32_16x16x32_bf16(wa[uv], bf, cb, 0, 0, 0);
            }
            if (g == 0)
                out[((long)b * TDIM + (t0 + grp)) * FDIM + f0 + lm] = ca[0] + cb[0] + bv;
        }
    }
}

extern "C" void kernel_launch(void* const* d_in, const int* in_sizes, int n_in,
                              void* d_out, int out_size, void* d_ws, size_t ws_size,
                              hipStream_t stream) {
    const float* pr    = (const float*)d_in[0];
    const float* onset = (const float*)d_in[1];
    const int*   tf    = (const int*)d_in[2];
    const float* W1 = (const float*)d_in[3];
    const float* B1 = (const float*)d_in[4];
    const float* W2 = (const float*)d_in[5];
    const float* B2 = (const float*)d_in[6];
    const float* W3 = (const float*)d_in[7];
    const float* B3 = (const float*)d_in[8];
    const float* W4 = (const float*)d_in[9];
    const float* B4 = (const float*)d_in[10];
    float* out = (float*)d_out;
    unsigned short* wt = (unsigned short*)d_ws;

    prep_weights_kernel<<<32, 256, 0, stream>>>(W1, W2, W3, W4, wt);

    dim3 gridI(6, 126, 8);   // interior: f0=(bx+1)*16 in [16,96], t0=(by+1)*16 in [16,2016]
    fused_mfma_kernel<false><<<gridI, 512, 0, stream>>>(pr, onset, tf, B1, B2, B3, B4, wt, out);

    dim3 gridE(268, 1, 8);   // edge frame blocks
    fused_mfma_kernel<true><<<gridE, 512, 0, stream>>>(pr, onset, tf, B1, B2, B3, B4, wt, out);
}